// Round 10
// baseline (122.792 us; speedup 1.0000x reference)
//
#include <hip/hip_runtime.h>

// Problem constants (from reference setup_inputs)
constexpr int Bb = 32;      // batch
constexpr int Mm = 65536;   // memory slots
constexpr int Ww = 32;      // word width
constexpr int Rr = 4;       // read heads
constexpr int Dd = 256;     // d_in
constexpr int Kk = 8;       // K_NEIGHBORS

constexpr int NB_A = 128;                   // blocks per batch, phase A
constexpr int TPB_A = 256;                  // threads per block
constexpr int ROWS_PER_BLOCK = Mm / NB_A;   // 512
constexpr int TILE_ROWS = 64;               // rows per LDS tile (4 thr/row)
constexpr int TILES = ROWS_PER_BLOCK / TILE_ROWS;  // 8
constexpr int NBUF = 4;                     // ring buffers (prefetch dist 3)
constexpr int CPL = NB_A * Kk / 64;         // final-merge candidates/lane = 16

// async global->LDS, 16 B per lane; LDS dest = uniform base + lane*16
__device__ __forceinline__ void glds16(const float4* src, float4* dst_lds) {
  __builtin_amdgcn_global_load_lds(
      (const __attribute__((address_space(1))) void*)src,
      (__attribute__((address_space(3))) void*)dst_lds, 16, 0, 0);
}

// ---------------------------------------------------------------------------
// Kernel 1: read_keys = xi @ W_rk^T + b_rk  (32 x 128), plus ||rk||^2 per (b,r)
// ---------------------------------------------------------------------------
__global__ __launch_bounds__(128) void rk_kernel(
    const float* __restrict__ xi, const float* __restrict__ Wrk,
    const float* __restrict__ brk, float* __restrict__ rk,
    float* __restrict__ rknorm) {
  const int b = blockIdx.x;
  const int tid = threadIdx.x;  // 128 threads = one rw each
  __shared__ float xs[Dd];
  __shared__ float rks[Rr * Ww];
  #pragma unroll
  for (int i = 0; i < Dd; i += 128) xs[i + tid] = xi[b * Dd + i + tid];
  __syncthreads();
  float acc = brk[tid];
  const float4* wr = reinterpret_cast<const float4*>(Wrk + (size_t)tid * Dd);
  #pragma unroll 4
  for (int i = 0; i < Dd / 4; ++i) {
    float4 wv = wr[i];
    acc = fmaf(wv.x, xs[4 * i + 0], acc);
    acc = fmaf(wv.y, xs[4 * i + 1], acc);
    acc = fmaf(wv.z, xs[4 * i + 2], acc);
    acc = fmaf(wv.w, xs[4 * i + 3], acc);
  }
  rk[b * Rr * Ww + tid] = acc;
  rks[tid] = acc;
  __syncthreads();
  if (tid < Rr) {
    float s = 0.f;
    #pragma unroll
    for (int j = 0; j < Ww; ++j) s = fmaf(rks[tid * Ww + j], rks[tid * Ww + j], s);
    rknorm[b * Rr + tid] = s;
  }
}

// ---------------------------------------------------------------------------
// Kernel 2: occupancy-first streaming. 64-row tiles (8 KB), ring-4 LDS
// (33 KB -> 4 blocks/CU = 16 waves), prefetch distance 3 with counted
// vmcnt(6) - 6 KB outstanding per wave. No barriers in the streaming loop
// (wave-private staging/reads). 4 threads/row (2 chunks = 8 floats each),
// 2-step shfl_xor finishes distances. Chunk XOR-swizzle: pre-swizzled
// GLOBAL source + swizzled LDS READ. d8 excludes rkn (added at cand
// write). Extraction: dedup'd dump into tile buf 0; wave w extracts head w.
// ---------------------------------------------------------------------------
__global__ __launch_bounds__(TPB_A)
__attribute__((amdgpu_waves_per_eu(4)))
void topk_partial(
    const float* __restrict__ sparse, const float* __restrict__ rk,
    const float* __restrict__ rknorm, float* __restrict__ cand_d,
    int* __restrict__ cand_i) {
  const int b = blockIdx.y;
  const int tid = threadIdx.x;
  const int lane = tid & 63;
  const int wid = tid >> 6;
  const float INF = __builtin_inff();

  __shared__ float4 rk4[Rr][8];                 // 512 B
  __shared__ float rkn_s[Rr];
  __shared__ float4 tile[NBUF][TILE_ROWS * 8];  // 4 x 8 KB

  // rk setup FIRST, barrier before any STAGE (avoid vmcnt drain at barrier)
  if (tid < Rr * Ww) reinterpret_cast<float*>(rk4)[tid] = rk[b * Rr * Ww + tid];
  if (tid < Rr) rkn_s[tid] = rknorm[b * Rr + tid];
  __syncthreads();

  const int rowBlk = blockIdx.x * ROWS_PER_BLOCK;
  const float4* sb4 =
      reinterpret_cast<const float4*>(sparse) + (size_t)b * Mm * 8;
  // staging source permutation: LDS slot (row, s) receives global chunk
  // s ^ (row&7); 8-row groups are aligned so row&7 == lane>>3 within a gload
  const int perm = ((lane >> 3) * 8) + ((lane & 7) ^ (lane >> 3));

  const int rowL = wid * 16 + (lane >> 2);  // local tile row (4 thr/row)
  const int rmask = rowL & 7;
  const int c0 = 2 * (lane & 3);            // this thread's 2 chunks

  // hoist this thread's rk fragments: 4 heads x 2 chunks = 32 VGPR
  float4 rkq[Rr][2];
  #pragma unroll
  for (int r = 0; r < Rr; ++r) {
    rkq[r][0] = rk4[r][c0];
    rkq[r][1] = rk4[r][c0 + 1];
  }

  float d8[Rr][TILES];

  // wave wid stages rows [wid*16, wid*16+16) of a tile: 2 x 1 KB gload_lds
  auto STAGE = [&](int buf, int t) {
    const float4* g0 = sb4 + (size_t)(rowBlk + t * TILE_ROWS + wid * 16) * 8;
    float4* l0 = &tile[buf][wid * 16 * 8];
    #pragma unroll
    for (int i = 0; i < 2; ++i) glds16(g0 + i * 64 + perm, l0 + i * 64);
  };

  STAGE(0, 0);
  STAGE(1, 1);
  STAGE(2, 2);
  #pragma unroll
  for (int t = 0; t < TILES; ++t) {
    if (t + 3 < TILES) {
      // this wave's reads of the buffer being overwritten are done (WAR)
      asm volatile("s_waitcnt lgkmcnt(0)" ::: "memory");
      STAGE((t + 3) % NBUF, t + 3);
      asm volatile("s_waitcnt vmcnt(6)" ::: "memory");  // tile t landed
    } else if (t + 2 < TILES) {
      asm volatile("s_waitcnt vmcnt(4)" ::: "memory");
    } else if (t + 1 < TILES) {
      asm volatile("s_waitcnt vmcnt(2)" ::: "memory");
    } else {
      asm volatile("s_waitcnt vmcnt(0)" ::: "memory");
    }
    const float4* tb = &tile[t % NBUF][rowL * 8];
    float a0 = 0.f, a1 = 0.f, a2 = 0.f, a3 = 0.f, ss = 0.f;
    #pragma unroll
    for (int j = 0; j < 2; ++j) {
      float4 v = tb[(c0 + j) ^ rmask];
      float4 k0 = rkq[0][j];
      float4 k1 = rkq[1][j];
      float4 k2 = rkq[2][j];
      float4 k3 = rkq[3][j];
      a0 = fmaf(k0.x, v.x, a0); a0 = fmaf(k0.y, v.y, a0);
      a0 = fmaf(k0.z, v.z, a0); a0 = fmaf(k0.w, v.w, a0);
      a1 = fmaf(k1.x, v.x, a1); a1 = fmaf(k1.y, v.y, a1);
      a1 = fmaf(k1.z, v.z, a1); a1 = fmaf(k1.w, v.w, a1);
      a2 = fmaf(k2.x, v.x, a2); a2 = fmaf(k2.y, v.y, a2);
      a2 = fmaf(k2.z, v.z, a2); a2 = fmaf(k2.w, v.w, a2);
      a3 = fmaf(k3.x, v.x, a3); a3 = fmaf(k3.y, v.y, a3);
      a3 = fmaf(k3.z, v.z, a3); a3 = fmaf(k3.w, v.w, a3);
      ss = fmaf(v.x, v.x, ss); ss = fmaf(v.y, v.y, ss);
      ss = fmaf(v.z, v.z, ss); ss = fmaf(v.w, v.w, ss);
    }
    // partial (d2 - rkn) per head over this quarter; 2-step butterfly sums
    float p0 = fmaf(-2.f, a0, ss);
    float p1 = fmaf(-2.f, a1, ss);
    float p2 = fmaf(-2.f, a2, ss);
    float p3 = fmaf(-2.f, a3, ss);
    p0 += __shfl_xor(p0, 1); p0 += __shfl_xor(p0, 2);
    p1 += __shfl_xor(p1, 1); p1 += __shfl_xor(p1, 2);
    p2 += __shfl_xor(p2, 1); p2 += __shfl_xor(p2, 2);
    p3 += __shfl_xor(p3, 1); p3 += __shfl_xor(p3, 2);
    d8[0][t] = p0;
    d8[1][t] = p1;
    d8[2][t] = p2;
    d8[3][t] = p3;
  }

  // --- extraction: dedup dump (one writer per row: lane&3==0) into tile
  //     buf 0 ([4 heads][512 rows] = 8 KB), then wave w extracts head w ---
  __syncthreads();  // all waves done reading tile bufs
  float* dmp = reinterpret_cast<float*>(&tile[0][0]);
  if ((lane & 3) == 0) {
    #pragma unroll
    for (int r = 0; r < Rr; ++r)
      #pragma unroll
      for (int t = 0; t < TILES; ++t)
        dmp[r * ROWS_PER_BLOCK + t * TILE_ROWS + rowL] = d8[r][t];
  }
  __syncthreads();

  {
    const int r = wid;  // wave w handles head w
    const float rknr = rkn_s[r];
    float v[TILES];     // v[i] = head r, local row i*64 + lane
    #pragma unroll
    for (int i = 0; i < TILES; ++i)
      v[i] = dmp[r * ROWS_PER_BLOCK + i * TILE_ROWS + lane];
    const int base = rowBlk + lane;  // slot i -> row base + i*64
    size_t o = ((size_t)(b * Rr + r) * NB_A + blockIdx.x) * Kk;
    #pragma unroll
    for (int k = 0; k < Kk; ++k) {
      // per-lane argmin over 8 static slots (rows ascending in i)
      float lv = v[0];
      int lrow = base;
      #pragma unroll
      for (int i = 1; i < TILES; ++i)
        if (v[i] < lv) { lv = v[i]; lrow = base + i * TILE_ROWS; }
      // wave butterfly argmin with index tie-break
      float bv = lv;
      int bi = lrow;
      #pragma unroll
      for (int off = 32; off; off >>= 1) {
        float ov = __shfl_xor(bv, off);
        int oi = __shfl_xor(bi, off);
        if (ov < bv || (ov == bv && oi < bi)) { bv = ov; bi = oi; }
      }
      if (lane == 0) { cand_d[o + k] = bv + rknr; cand_i[o + k] = bi; }
      // winner slot (value AND row match) -> INF; static indexing
      #pragma unroll
      for (int i = 0; i < TILES; ++i) {
        bool clr = (v[i] == bv) && (base + i * TILE_ROWS == bi);
        v[i] = clr ? INF : v[i];
      }
    }
  }
}

// ---------------------------------------------------------------------------
// Kernel 3: merge 128*8 candidates per (b,r) -> global top-8, weights, gather
// ---------------------------------------------------------------------------
__global__ __launch_bounds__(64) void topk_final(
    const float* __restrict__ sparse, const float* __restrict__ cand_d,
    const int* __restrict__ cand_i, float* __restrict__ out) {
  const int br = blockIdx.x;  // b*4 + r
  const int b = br >> 2;
  const int r = br & 3;
  const int lane = threadIdx.x;  // 64
  const float INF = __builtin_inff();

  float ld[CPL];
  int li[CPL];
  const float* cd = cand_d + (size_t)br * (NB_A * Kk);
  const int* ci = cand_i + (size_t)br * (NB_A * Kk);
  #pragma unroll
  for (int t = 0; t < CPL; ++t) {
    ld[t] = cd[t * 64 + lane];
    li[t] = ci[t * 64 + lane];
  }
  // sort per-lane list ascending (static bubble network)
  #pragma unroll
  for (int i = 0; i < CPL - 1; ++i)
    #pragma unroll
    for (int j = 0; j < CPL - 1 - i; ++j)
      if (ld[j + 1] < ld[j] || (ld[j + 1] == ld[j] && li[j + 1] < li[j])) {
        float td = ld[j]; ld[j] = ld[j + 1]; ld[j + 1] = td;
        int ti = li[j]; li[j] = li[j + 1]; li[j + 1] = ti;
      }

  __shared__ float s_td[Kk];
  __shared__ int s_ti[Kk];
  #pragma unroll
  for (int k = 0; k < Kk; ++k) {
    float v = ld[0];
    int id = li[0];
    #pragma unroll
    for (int off = 32; off; off >>= 1) {  // butterfly: all lanes get the min
      float ov = __shfl_xor(v, off);
      int oi = __shfl_xor(id, off);
      if (ov < v || (ov == v && oi < id)) { v = ov; id = oi; }
    }
    if (lane == 0) { s_td[k] = v; s_ti[k] = id; }
    if (li[0] == id) {  // owner pops head
      #pragma unroll
      for (int j = 0; j < CPL - 1; ++j) { ld[j] = ld[j + 1]; li[j] = li[j + 1]; }
      ld[CPL - 1] = INF;
      li[CPL - 1] = -1;
    }
  }
  __syncthreads();

  // read_weights[r][b][k] = dist_k / dist_7  (dist ascending -> max is last)
  const float dmax = s_td[Kk - 1];
  if (lane < Kk)
    out[(size_t)Rr * Bb * Kk * Ww + ((size_t)r * Bb + b) * Kk + lane] =
        s_td[lane] / dmax;

  // read_vectors[r][b][k][j] = sparse[b][idx_k][j]
  const float* sbase = sparse + (size_t)b * Mm * Ww;
  #pragma unroll
  for (int t = 0; t < (Kk * Ww) / 64; ++t) {
    int e = t * 64 + lane;
    int k = e >> 5;
    int j = e & 31;
    out[(((size_t)r * Bb + b) * Kk + k) * Ww + j] =
        sbase[(size_t)s_ti[k] * Ww + j];
  }
}

// ---------------------------------------------------------------------------
extern "C" void kernel_launch(void* const* d_in, const int* in_sizes, int n_in,
                              void* d_out, int out_size, void* d_ws,
                              size_t ws_size, hipStream_t stream) {
  const float* xi = (const float*)d_in[0];
  const float* sparse = (const float*)d_in[1];
  const float* Wrk = (const float*)d_in[2];
  const float* brk = (const float*)d_in[3];
  float* out = (float*)d_out;

  char* ws = (char*)d_ws;
  float* rk = (float*)ws;                          // 32*128*4       = 16384 B
  float* rknorm = (float*)(ws + 16384);            // 128*4          = 512 B
  float* cand_d = (float*)(ws + 16896);            // 32*4*128*8*4   = 524288 B
  int* cand_i = (int*)(ws + 16896 + 524288);       // 524288 B

  rk_kernel<<<Bb, 128, 0, stream>>>(xi, Wrk, brk, rk, rknorm);
  dim3 gridA(NB_A, Bb);
  topk_partial<<<gridA, TPB_A, 0, stream>>>(sparse, rk, rknorm, cand_d, cand_i);
  topk_final<<<Bb * Rr, 64, 0, stream>>>(sparse, cand_d, cand_i, out);
}

// Round 11
// 91.839 us; speedup vs baseline: 1.3370x; 1.3370x over previous
//
#include <hip/hip_runtime.h>

// Problem constants (from reference setup_inputs)
constexpr int Bb = 32;      // batch
constexpr int Mm = 65536;   // memory slots
constexpr int Ww = 32;      // word width
constexpr int Rr = 4;       // read heads
constexpr int Dd = 256;     // d_in
constexpr int Kk = 8;       // K_NEIGHBORS

constexpr int NB_A = 64;                    // blocks per batch, phase A
constexpr int TPB_A = 256;                  // threads per block
constexpr int ROWS_PER_BLOCK = Mm / NB_A;   // 1024
constexpr int TILE_ROWS = 128;              // rows per LDS tile (2 thr/row)
constexpr int TILES = ROWS_PER_BLOCK / TILE_ROWS;  // 8
constexpr int NBUF = 3;                     // ring buffers (prefetch dist 2)
constexpr int GRP_F4 = 65;                  // float4 per 8-row group (64 + 1 pad)
constexpr int TILE_F4 = (TILE_ROWS / 8) * GRP_F4;  // 1040 float4 = 16640 B
constexpr int CPL = NB_A * Kk / 64;         // final-merge candidates/lane = 8

// async global->LDS, 16 B per lane; LDS dest = uniform base + lane*16
__device__ __forceinline__ void glds16(const float4* src, float4* dst_lds) {
  __builtin_amdgcn_global_load_lds(
      (const __attribute__((address_space(1))) void*)src,
      (__attribute__((address_space(3))) void*)dst_lds, 16, 0, 0);
}

// ---------------------------------------------------------------------------
// Kernel 1: read_keys = xi @ W_rk^T + b_rk  (32 x 128), plus ||rk||^2 per (b,r)
// ---------------------------------------------------------------------------
__global__ __launch_bounds__(128) void rk_kernel(
    const float* __restrict__ xi, const float* __restrict__ Wrk,
    const float* __restrict__ brk, float* __restrict__ rk,
    float* __restrict__ rknorm) {
  const int b = blockIdx.x;
  const int tid = threadIdx.x;  // 128 threads = one rw each
  __shared__ float xs[Dd];
  __shared__ float rks[Rr * Ww];
  #pragma unroll
  for (int i = 0; i < Dd; i += 128) xs[i + tid] = xi[b * Dd + i + tid];
  __syncthreads();
  float acc = brk[tid];
  const float4* wr = reinterpret_cast<const float4*>(Wrk + (size_t)tid * Dd);
  #pragma unroll 4
  for (int i = 0; i < Dd / 4; ++i) {
    float4 wv = wr[i];
    acc = fmaf(wv.x, xs[4 * i + 0], acc);
    acc = fmaf(wv.y, xs[4 * i + 1], acc);
    acc = fmaf(wv.z, xs[4 * i + 2], acc);
    acc = fmaf(wv.w, xs[4 * i + 3], acc);
  }
  rk[b * Rr * Ww + tid] = acc;
  rks[tid] = acc;
  __syncthreads();
  if (tid < Rr) {
    float s = 0.f;
    #pragma unroll
    for (int j = 0; j < Ww; ++j) s = fmaf(rks[tid * Ww + j], rks[tid * Ww + j], s);
    rknorm[b * Rr + tid] = s;
  }
}

// ---------------------------------------------------------------------------
// Kernel 2 (= round-7 champion, ONE change: linear gload_lds source +
// 16B-pad-per-8-row-group LDS layout instead of the chunk XOR-swizzle).
// Ring-3 gload_lds pipeline, prefetch distance 2, counted vmcnt, no
// barriers in the streaming loop (wave-private staging/reads). 128-row
// tiles, 2 threads/row, one shfl_xor(1) per head finishes each distance.
// Group stride 1040 B shifts bank mapping 4 dwords per group -> row-chunk
// reads are 8-way (not 32-way) conflicted; gload_lds sources are perfectly
// lane-monotonic (coalescer test). rk fragments re-read from LDS per tile
// (broadcast reads) - registers stay low, occupancy at the 3-block LDS cap.
// ---------------------------------------------------------------------------
__global__ __launch_bounds__(TPB_A, 2) void topk_partial(
    const float* __restrict__ sparse, const float* __restrict__ rk,
    const float* __restrict__ rknorm, float* __restrict__ cand_d,
    int* __restrict__ cand_i) {
  const int b = blockIdx.y;
  const int tid = threadIdx.x;
  const int lane = tid & 63;
  const int wid = tid >> 6;
  const float INF = __builtin_inff();

  __shared__ float4 rk4[Rr][8];               // 512 B
  __shared__ float rkn_s[Rr];
  __shared__ float4 tile[NBUF][TILE_F4];      // 3 x 16640 B

  if (tid < Rr * Ww) reinterpret_cast<float*>(rk4)[tid] = rk[b * Rr * Ww + tid];
  if (tid < Rr) rkn_s[tid] = rknorm[b * Rr + tid];
  __syncthreads();

  float rkn[Rr];
  #pragma unroll
  for (int r = 0; r < Rr; ++r) rkn[r] = rkn_s[r];

  const int rowBlk = blockIdx.x * ROWS_PER_BLOCK;
  const float4* sb4 =
      reinterpret_cast<const float4*>(sparse) + (size_t)b * Mm * 8;

  const int rowL = wid * 32 + (lane >> 1);  // local tile row (2 thr/row)
  const int hsel = (tid & 1) * 4;           // this thread's 4 chunks
  // padded-layout base: group (rowL>>3) at stride 65 float4, row-in-group *8
  const int rbase = (rowL >> 3) * GRP_F4 + (rowL & 7) * 8;

  float d8[Rr][TILES];

  // wave wid stages rows [wid*32, wid*32+32) of a tile: 4 x 1 KB gload_lds,
  // one 8-row group each, source lane-monotonic, dest 16B-aligned contiguous
  auto STAGE = [&](int buf, int t) {
    const float4* g0 = sb4 + (size_t)(rowBlk + t * TILE_ROWS + wid * 32) * 8;
    #pragma unroll
    for (int i = 0; i < 4; ++i)
      glds16(g0 + i * 64 + lane, &tile[buf][(wid * 4 + i) * GRP_F4]);
  };

  STAGE(0, 0);
  STAGE(1, 1);
  #pragma unroll
  for (int t = 0; t < TILES; ++t) {
    if (t + 2 < TILES) {
      // this wave's reads of the buffer being overwritten are done (WAR)
      asm volatile("s_waitcnt lgkmcnt(0)" ::: "memory");
      STAGE((t + 2) % NBUF, t + 2);
      asm volatile("s_waitcnt vmcnt(8)" ::: "memory");  // tile t landed
    } else if (t + 1 < TILES) {
      asm volatile("s_waitcnt vmcnt(4)" ::: "memory");  // tile t landed
    } else {
      asm volatile("s_waitcnt vmcnt(0)" ::: "memory");
    }
    const float4* tb = &tile[t % NBUF][rbase];
    float a0 = 0.f, a1 = 0.f, a2 = 0.f, a3 = 0.f, ss = 0.f;
    #pragma unroll
    for (int j = 0; j < 4; ++j) {
      float4 v = tb[hsel + j];
      float4 k0 = rk4[0][hsel + j];
      float4 k1 = rk4[1][hsel + j];
      float4 k2 = rk4[2][hsel + j];
      float4 k3 = rk4[3][hsel + j];
      a0 = fmaf(k0.x, v.x, a0); a0 = fmaf(k0.y, v.y, a0);
      a0 = fmaf(k0.z, v.z, a0); a0 = fmaf(k0.w, v.w, a0);
      a1 = fmaf(k1.x, v.x, a1); a1 = fmaf(k1.y, v.y, a1);
      a1 = fmaf(k1.z, v.z, a1); a1 = fmaf(k1.w, v.w, a1);
      a2 = fmaf(k2.x, v.x, a2); a2 = fmaf(k2.y, v.y, a2);
      a2 = fmaf(k2.z, v.z, a2); a2 = fmaf(k2.w, v.w, a2);
      a3 = fmaf(k3.x, v.x, a3); a3 = fmaf(k3.y, v.y, a3);
      a3 = fmaf(k3.z, v.z, a3); a3 = fmaf(k3.w, v.w, a3);
      ss = fmaf(v.x, v.x, ss); ss = fmaf(v.y, v.y, ss);
      ss = fmaf(v.z, v.z, ss); ss = fmaf(v.w, v.w, ss);
    }
    // partial d2 per head = ss - 2*dot over this half; partner adds the rest
    float p0 = fmaf(-2.f, a0, ss);
    float p1 = fmaf(-2.f, a1, ss);
    float p2 = fmaf(-2.f, a2, ss);
    float p3 = fmaf(-2.f, a3, ss);
    p0 += __shfl_xor(p0, 1);
    p1 += __shfl_xor(p1, 1);
    p2 += __shfl_xor(p2, 1);
    p3 += __shfl_xor(p3, 1);
    d8[0][t] = p0 + rkn[0];
    d8[1][t] = p1 + rkn[1];
    d8[2][t] = p2 + rkn[2];
    d8[3][t] = p3 + rkn[3];
  }

  // --- extraction: dedup (even threads only; local row == tid/2), dump to
  //     LDS (reuses tile buf 0: 16640 B >= 16 KB), wave w extracts head w ---
  __syncthreads();  // all waves done streaming (tile bufs free)
  float* dmp = reinterpret_cast<float*>(&tile[0][0]);  // [4][128][8] = 16 KB
  if ((tid & 1) == 0) {
    const int e = tid >> 1;  // == this thread's local row
    #pragma unroll
    for (int r = 0; r < Rr; ++r) {
      float4* p = reinterpret_cast<float4*>(&dmp[(r * 128 + e) * 8]);
      p[0] = make_float4(d8[r][0], d8[r][1], d8[r][2], d8[r][3]);
      p[1] = make_float4(d8[r][4], d8[r][5], d8[r][6], d8[r][7]);
    }
  }
  __syncthreads();

  {
    const int r = wid;          // wave w handles head w
    const int e0 = 2 * lane;    // this lane's two local rows
    float v[2][TILES];
    #pragma unroll
    for (int q = 0; q < 2; ++q) {
      const float4* p =
          reinterpret_cast<const float4*>(&dmp[(r * 128 + e0 + q) * 8]);
      float4 lo = p[0], hi = p[1];
      v[q][0] = lo.x; v[q][1] = lo.y; v[q][2] = lo.z; v[q][3] = lo.w;
      v[q][4] = hi.x; v[q][5] = hi.y; v[q][6] = hi.z; v[q][7] = hi.w;
    }
    const int base = rowBlk + e0;  // row = base + q + s*TILE_ROWS
    size_t o = ((size_t)(b * Rr + r) * NB_A + blockIdx.x) * Kk;
    #pragma unroll
    for (int k = 0; k < Kk; ++k) {
      // per-lane argmin over 16 static slots with global-row tie-break
      float lv = v[0][0];
      int lrow = base;
      #pragma unroll
      for (int q = 0; q < 2; ++q)
        #pragma unroll
        for (int s = 0; s < TILES; ++s) {
          if (q == 0 && s == 0) continue;
          int row = base + q + s * TILE_ROWS;
          if (v[q][s] < lv || (v[q][s] == lv && row < lrow)) {
            lv = v[q][s]; lrow = row;
          }
        }
      // wave butterfly argmin
      float bv = lv;
      int bi = lrow;
      #pragma unroll
      for (int off = 32; off; off >>= 1) {
        float ov = __shfl_xor(bv, off);
        int oi = __shfl_xor(bi, off);
        if (ov < bv || (ov == bv && oi < bi)) { bv = ov; bi = oi; }
      }
      if (lane == 0) { cand_d[o + k] = bv; cand_i[o + k] = bi; }
      // winner slot (value AND row match) -> INF; static indexing
      #pragma unroll
      for (int q = 0; q < 2; ++q)
        #pragma unroll
        for (int s = 0; s < TILES; ++s) {
          bool clr = (v[q][s] == bv) && (base + q + s * TILE_ROWS == bi);
          v[q][s] = clr ? INF : v[q][s];
        }
    }
  }
}

// ---------------------------------------------------------------------------
// Kernel 3: merge 64*8 candidates per (b,r) -> global top-8, weights, gather
// ---------------------------------------------------------------------------
__global__ __launch_bounds__(64) void topk_final(
    const float* __restrict__ sparse, const float* __restrict__ cand_d,
    const int* __restrict__ cand_i, float* __restrict__ out) {
  const int br = blockIdx.x;  // b*4 + r
  const int b = br >> 2;
  const int r = br & 3;
  const int lane = threadIdx.x;  // 64
  const float INF = __builtin_inff();

  float ld[CPL];
  int li[CPL];
  const float* cd = cand_d + (size_t)br * (NB_A * Kk);
  const int* ci = cand_i + (size_t)br * (NB_A * Kk);
  #pragma unroll
  for (int t = 0; t < CPL; ++t) {
    ld[t] = cd[t * 64 + lane];
    li[t] = ci[t * 64 + lane];
  }
  // sort per-lane list ascending (static bubble network)
  #pragma unroll
  for (int i = 0; i < CPL - 1; ++i)
    #pragma unroll
    for (int j = 0; j < CPL - 1 - i; ++j)
      if (ld[j + 1] < ld[j] || (ld[j + 1] == ld[j] && li[j + 1] < li[j])) {
        float td = ld[j]; ld[j] = ld[j + 1]; ld[j + 1] = td;
        int ti = li[j]; li[j] = li[j + 1]; li[j + 1] = ti;
      }

  __shared__ float s_td[Kk];
  __shared__ int s_ti[Kk];
  #pragma unroll
  for (int k = 0; k < Kk; ++k) {
    float v = ld[0];
    int id = li[0];
    #pragma unroll
    for (int off = 32; off; off >>= 1) {  // butterfly: all lanes get the min
      float ov = __shfl_xor(v, off);
      int oi = __shfl_xor(id, off);
      if (ov < v || (ov == v && oi < id)) { v = ov; id = oi; }
    }
    if (lane == 0) { s_td[k] = v; s_ti[k] = id; }
    if (li[0] == id) {  // owner pops head
      #pragma unroll
      for (int j = 0; j < CPL - 1; ++j) { ld[j] = ld[j + 1]; li[j] = li[j + 1]; }
      ld[CPL - 1] = INF;
      li[CPL - 1] = -1;
    }
  }
  __syncthreads();

  // read_weights[r][b][k] = dist_k / dist_7  (dist ascending -> max is last)
  const float dmax = s_td[Kk - 1];
  if (lane < Kk)
    out[(size_t)Rr * Bb * Kk * Ww + ((size_t)r * Bb + b) * Kk + lane] =
        s_td[lane] / dmax;

  // read_vectors[r][b][k][j] = sparse[b][idx_k][j]
  const float* sbase = sparse + (size_t)b * Mm * Ww;
  #pragma unroll
  for (int t = 0; t < (Kk * Ww) / 64; ++t) {
    int e = t * 64 + lane;
    int k = e >> 5;
    int j = e & 31;
    out[(((size_t)r * Bb + b) * Kk + k) * Ww + j] =
        sbase[(size_t)s_ti[k] * Ww + j];
  }
}

// ---------------------------------------------------------------------------
extern "C" void kernel_launch(void* const* d_in, const int* in_sizes, int n_in,
                              void* d_out, int out_size, void* d_ws,
                              size_t ws_size, hipStream_t stream) {
  const float* xi = (const float*)d_in[0];
  const float* sparse = (const float*)d_in[1];
  const float* Wrk = (const float*)d_in[2];
  const float* brk = (const float*)d_in[3];
  float* out = (float*)d_out;

  char* ws = (char*)d_ws;
  float* rk = (float*)ws;                          // 32*128*4      = 16384 B
  float* rknorm = (float*)(ws + 16384);            // 128*4         = 512 B
  float* cand_d = (float*)(ws + 16896);            // 32*4*64*8*4   = 262144 B
  int* cand_i = (int*)(ws + 16896 + 262144);       // 262144 B

  rk_kernel<<<Bb, 128, 0, stream>>>(xi, Wrk, brk, rk, rknorm);
  dim3 gridA(NB_A, Bb);
  topk_partial<<<gridA, TPB_A, 0, stream>>>(sparse, rk, rknorm, cand_d, cand_i);
  topk_final<<<Bb * Rr, 64, 0, stream>>>(sparse, cand_d, cand_i, out);
}